// Round 10
// baseline (394.086 us; speedup 1.0000x reference)
//
#include <hip/hip_runtime.h>
#include <hip/hip_bf16.h>

#define N_DIM 128
#define NHEADS 4
#define HEAD_DIM 32

typedef unsigned short bf16_t;
typedef short bf16x8 __attribute__((ext_vector_type(8)));
typedef float f32x4 __attribute__((ext_vector_type(4)));

__device__ __forceinline__ float bf16_to_f32(unsigned int u16) {
    union { unsigned int i; float f; } x;
    x.i = u16 << 16;
    return x.f;
}

// low/high bf16 of a packed uint -> f32
__device__ __forceinline__ float lof(unsigned int u) {
    union { unsigned int i; float f; } x; x.i = u << 16; return x.f;
}
__device__ __forceinline__ float hif(unsigned int u) {
    union { unsigned int i; float f; } x; x.i = u & 0xffff0000u; return x.f;
}

__device__ __forceinline__ bf16_t f32_to_bf16(float f) {
    union { float f; unsigned int i; } x;
    x.f = f;
    unsigned int r = x.i + 0x7FFFu + ((x.i >> 16) & 1u);  // RNE
    return (bf16_t)(r >> 16);
}

__device__ __forceinline__ float dot2(unsigned int a, unsigned int b, float acc) {
    acc = fmaf(lof(a), lof(b), acc);
    acc = fmaf(hif(a), hif(b), acc);
    return acc;
}

// padded LDS stride for the 32x128 bf16 A-tile: 136 elems = 272 B
#define LDA_STRIDE 136

// ---------------------------------------------------------------------------
// K0: transpose W's to bf16.  Wt[384][128] = {Wq^T,Wk^T,Wv^T}, Wot = Wo^T.
// ---------------------------------------------------------------------------
__global__ __launch_bounds__(128) void transpose_w_kernel(
    const float* __restrict__ Wq, const float* __restrict__ Wk,
    const float* __restrict__ Wv, const float* __restrict__ Wo,
    bf16_t* __restrict__ Wt, bf16_t* __restrict__ Wot)
{
    const int n = blockIdx.x;    // 0..511
    const int k = threadIdx.x;   // 0..127
    const float* W; bf16_t* dst; int nl;
    if (n < 128)      { W = Wq; nl = n;       dst = Wt  + n * 128; }
    else if (n < 256) { W = Wk; nl = n - 128; dst = Wt  + n * 128; }
    else if (n < 384) { W = Wv; nl = n - 256; dst = Wt  + n * 128; }
    else              { W = Wo; nl = n - 384; dst = Wot + (n - 384) * 128; }
    dst[k] = f32_to_bf16(W[k * 128 + nl]);
}

// ---------------------------------------------------------------------------
// K1 (MFMA): q/k/v projections, bf16 out.  (measured-good, unchanged)
// ---------------------------------------------------------------------------
__global__ __launch_bounds__(256) void qkv_mfma_kernel(
    const float* __restrict__ nodes,
    const bf16_t* __restrict__ Wt,
    const float* __restrict__ bq, const float* __restrict__ bk,
    const float* __restrict__ bv,
    bf16_t* __restrict__ qb, bf16_t* __restrict__ kb, bf16_t* __restrict__ vb,
    int N)
{
    __shared__ bf16_t lds_a[32 * LDA_STRIDE];
    const int tid = threadIdx.x;
    const int m0 = blockIdx.x * 32;

#pragma unroll
    for (int i = 0; i < 4; ++i) {
        const int f = tid + 256 * i;
        const int row = f >> 5, c4 = f & 31;
        const int g = m0 + row;
        float4 v = make_float4(0.f, 0.f, 0.f, 0.f);
        if (g < N) v = ((const float4*)nodes)[(size_t)g * 32 + c4];
        ushort4 u;
        u.x = f32_to_bf16(v.x); u.y = f32_to_bf16(v.y);
        u.z = f32_to_bf16(v.z); u.w = f32_to_bf16(v.w);
        *(ushort4*)(lds_a + row * LDA_STRIDE + c4 * 4) = u;
    }
    __syncthreads();

    const int w  = tid >> 6;
    const int l  = tid & 63;
    const int lr = l & 15;
    const int lg = l >> 4;

    bf16x8 a[2][4];
#pragma unroll
    for (int mt = 0; mt < 2; ++mt)
#pragma unroll
        for (int kt = 0; kt < 4; ++kt)
            a[mt][kt] = *(const bf16x8*)(lds_a + (mt * 16 + lr) * LDA_STRIDE
                                         + kt * 32 + lg * 8);

#pragma unroll
    for (int ni = 0; ni < 6; ++ni) {
        const int nt = w * 6 + ni;
        const int col = nt * 16 + lr;
        f32x4 acc0 = {0.f, 0.f, 0.f, 0.f};
        f32x4 acc1 = {0.f, 0.f, 0.f, 0.f};
#pragma unroll
        for (int kt = 0; kt < 4; ++kt) {
            const bf16x8 b = *(const bf16x8*)(Wt + (size_t)col * 128
                                              + kt * 32 + lg * 8);
            acc0 = __builtin_amdgcn_mfma_f32_16x16x32_bf16(a[0][kt], b, acc0, 0, 0, 0);
            acc1 = __builtin_amdgcn_mfma_f32_16x16x32_bf16(a[1][kt], b, acc1, 0, 0, 0);
        }
        bf16_t* dst; int cl; const float* bias;
        if (nt < 8)       { dst = qb; cl = col;       bias = bq; }
        else if (nt < 16) { dst = kb; cl = col - 128; bias = bk; }
        else              { dst = vb; cl = col - 256; bias = bv; }
        const float bb = bias[cl];
#pragma unroll
        for (int j = 0; j < 4; ++j) {
            const int r0 = m0 + lg * 4 + j;
            if (r0 < N) dst[(size_t)r0 * 128 + cl] = f32_to_bf16(acc0[j] + bb);
            const int r1 = m0 + 16 + lg * 4 + j;
            if (r1 < N) dst[(size_t)r1 * 128 + cl] = f32_to_bf16(acc1[j] + bb);
        }
    }
}

// ---------------------------------------------------------------------------
// K2a: one LANE per edge -- 4 head dots + softmax, no shuffles.
// attn2[e*2+0] = {w0,w1} bf16-packed, [e*2+1] = {w2,w3}.
// ---------------------------------------------------------------------------
__global__ __launch_bounds__(256) void edge_attn_kernel(
    const int* __restrict__ senders, const int* __restrict__ receivers,
    const bf16_t* __restrict__ qb, const bf16_t* __restrict__ kb,
    unsigned int* __restrict__ attn2, int E)
{
    const int e = blockIdx.x * 256 + threadIdx.x;
    if (e >= E) return;
    const uint4* qr = (const uint4*)(qb + (size_t)senders[e] * N_DIM);
    const uint4* kr = (const uint4*)(kb + (size_t)receivers[e] * N_DIM);

    float d[4];
#pragma unroll
    for (int h = 0; h < 4; ++h) {
        float acc = 0.f;
#pragma unroll
        for (int i = 0; i < 4; ++i) {
            const uint4 qu = qr[h * 4 + i];
            const uint4 ku = kr[h * 4 + i];
            acc = dot2(qu.x, ku.x, acc);
            acc = dot2(qu.y, ku.y, acc);
            acc = dot2(qu.z, ku.z, acc);
            acc = dot2(qu.w, ku.w, acc);
        }
        d[h] = acc * 0.17677669529663687f;  // 1/sqrt(32)
    }

    const float m = fmaxf(fmaxf(d[0], d[1]), fmaxf(d[2], d[3]));
    float e0 = __expf(d[0] - m), e1 = __expf(d[1] - m);
    float e2 = __expf(d[2] - m), e3 = __expf(d[3] - m);
    const float inv = 1.f / (e0 + e1 + e2 + e3);
    e0 *= inv; e1 *= inv; e2 *= inv; e3 *= inv;

    attn2[(size_t)e * 2 + 0] =
        (unsigned)f32_to_bf16(e0) | ((unsigned)f32_to_bf16(e1) << 16);
    attn2[(size_t)e * 2 + 1] =
        (unsigned)f32_to_bf16(e2) | ((unsigned)f32_to_bf16(e3) << 16);
}

// ---------------------------------------------------------------------------
// CSR build: histogram -> 2-level exclusive scan -> scatter (+weight reorder)
// ---------------------------------------------------------------------------
__global__ __launch_bounds__(256) void hist_kernel(
    const int* __restrict__ receivers, int* __restrict__ cnt, int E)
{
    const int i = blockIdx.x * 256 + threadIdx.x;
    if (i < E) atomicAdd(&cnt[receivers[i]], 1);
}

__global__ __launch_bounds__(256) void scan_block_kernel(
    const int* __restrict__ cnt, int* __restrict__ starts,
    int* __restrict__ bsum, int N)
{
    __shared__ int sc[256];
    const int t = threadIdx.x;
    const int base = blockIdx.x * 1024 + t * 4;
    int v0 = (base + 0 < N) ? cnt[base + 0] : 0;
    int v1 = (base + 1 < N) ? cnt[base + 1] : 0;
    int v2 = (base + 2 < N) ? cnt[base + 2] : 0;
    int v3 = (base + 3 < N) ? cnt[base + 3] : 0;
    const int s = v0 + v1 + v2 + v3;
    sc[t] = s;
    __syncthreads();
    for (int off = 1; off < 256; off <<= 1) {
        int x = (t >= off) ? sc[t - off] : 0;
        __syncthreads();
        sc[t] += x;
        __syncthreads();
    }
    int excl = sc[t] - s;
    if (base + 0 < N) starts[base + 0] = excl;
    if (base + 1 < N) starts[base + 1] = excl + v0;
    if (base + 2 < N) starts[base + 2] = excl + v0 + v1;
    if (base + 3 < N) starts[base + 3] = excl + v0 + v1 + v2;
    if (t == 255) bsum[blockIdx.x] = sc[255];
}

__global__ __launch_bounds__(256) void scan_top_kernel(
    const int* __restrict__ bsum, int* __restrict__ boff,
    int* __restrict__ starts, int nb, int N)
{
    __shared__ int sc[256];
    const int t = threadIdx.x;
    const int s = (t < nb) ? bsum[t] : 0;
    sc[t] = s;
    __syncthreads();
    for (int off = 1; off < 256; off <<= 1) {
        int x = (t >= off) ? sc[t - off] : 0;
        __syncthreads();
        sc[t] += x;
        __syncthreads();
    }
    if (t < nb) boff[t] = sc[t] - s;
    if (t == 255) starts[N] = sc[255];
}

__global__ __launch_bounds__(256) void scan_add_kernel(
    int* __restrict__ starts, int* __restrict__ cursor,
    const int* __restrict__ boff, int N)
{
    const int t = threadIdx.x;
    const int base = blockIdx.x * 1024 + t * 4;
    const int o = boff[blockIdx.x];
#pragma unroll
    for (int k = 0; k < 4; ++k) {
        const int i = base + k;
        if (i < N) {
            const int v = starts[i] + o;
            starts[i] = v;
            cursor[i] = v;
        }
    }
}

__global__ __launch_bounds__(256) void scatter_kernel(
    const int* __restrict__ senders, const int* __restrict__ receivers,
    const unsigned int* __restrict__ attn2,
    int* __restrict__ cursor, int* __restrict__ elist,
    unsigned int* __restrict__ wlist2, int E)
{
    const int i = blockIdx.x * 256 + threadIdx.x;
    if (i < E) {
        const int pos = atomicAdd(&cursor[receivers[i]], 1);
        elist[pos] = senders[i];
        ((uint2*)wlist2)[pos] = ((const uint2*)attn2)[i];
    }
}

// ---------------------------------------------------------------------------
// K2b (CSR aggregate): one wave per receiver.  Per edge: 1 shfl (sender),
// 1 broadcast weight load, 1 coalesced v-row load, 2 FMA.  No atomics.
// ---------------------------------------------------------------------------
__global__ __launch_bounds__(256) void agg2_kernel(
    const int* __restrict__ starts, const int* __restrict__ elist,
    const unsigned int* __restrict__ wlist2,
    const bf16_t* __restrict__ vb,
    bf16_t* __restrict__ agg_b, int N)
{
    const int r = blockIdx.x * 4 + (threadIdx.x >> 6);
    const int lane = threadIdx.x & 63;
    if (r >= N) return;

    const int start = starts[r];
    const int end   = starts[r + 1];
    const int c = lane * 2;
    const int h = lane >> 4;
    const int hw = h >> 1;          // which packed uint
    const int hs = h & 1;           // lo/hi half

    float ax = 0.f, ay = 0.f;

    for (int j0 = start; j0 < end; j0 += 64) {
        const int ids = (j0 + lane < end) ? elist[j0 + lane] : 0;
        const int jm = min(64, end - j0);
        for (int j = 0; j < jm; ++j) {
            const int s = __shfl(ids, j);
            const unsigned int wu = wlist2[(size_t)(j0 + j) * 2 + hw];
            const float w = hs ? hif(wu) : lof(wu);
            const unsigned int vu =
                *(const unsigned int*)(vb + (size_t)s * N_DIM + c);
            ax = fmaf(lof(vu), w, ax);
            ay = fmaf(hif(vu), w, ay);
        }
    }

    const unsigned int packed =
        (unsigned int)f32_to_bf16(ax) | ((unsigned int)f32_to_bf16(ay) << 16);
    *(unsigned int*)(agg_b + (size_t)r * N_DIM + c) = packed;
}

// ---------------------------------------------------------------------------
// K3 (MFMA): out = agg_b @ Wo + bo + nodes.  Stages bf16 agg directly.
// ---------------------------------------------------------------------------
__global__ __launch_bounds__(256) void out_mfma_b_kernel(
    const float* __restrict__ nodes,
    const bf16_t* __restrict__ agg_b,
    const bf16_t* __restrict__ Wot,
    const float* __restrict__ bo,
    float* __restrict__ out, int N)
{
    __shared__ bf16_t lds_a[32 * LDA_STRIDE];
    const int tid = threadIdx.x;
    const int m0 = blockIdx.x * 32;

#pragma unroll
    for (int i = 0; i < 4; ++i) {
        const int f = tid + 256 * i;
        const int row = f >> 5, c4 = f & 31;
        const int g = m0 + row;
        ushort4 u = make_ushort4(0, 0, 0, 0);
        if (g < N) u = ((const ushort4*)(agg_b + (size_t)g * N_DIM))[c4];
        *(ushort4*)(lds_a + row * LDA_STRIDE + c4 * 4) = u;
    }
    __syncthreads();

    const int w  = tid >> 6;
    const int l  = tid & 63;
    const int lr = l & 15;
    const int lg = l >> 4;

    bf16x8 a[2][4];
#pragma unroll
    for (int mt = 0; mt < 2; ++mt)
#pragma unroll
        for (int kt = 0; kt < 4; ++kt)
            a[mt][kt] = *(const bf16x8*)(lds_a + (mt * 16 + lr) * LDA_STRIDE
                                         + kt * 32 + lg * 8);

#pragma unroll
    for (int ni = 0; ni < 2; ++ni) {
        const int nt = w * 2 + ni;
        const int col = nt * 16 + lr;
        f32x4 acc0 = {0.f, 0.f, 0.f, 0.f};
        f32x4 acc1 = {0.f, 0.f, 0.f, 0.f};
#pragma unroll
        for (int kt = 0; kt < 4; ++kt) {
            const bf16x8 b = *(const bf16x8*)(Wot + (size_t)col * 128
                                              + kt * 32 + lg * 8);
            acc0 = __builtin_amdgcn_mfma_f32_16x16x32_bf16(a[0][kt], b, acc0, 0, 0, 0);
            acc1 = __builtin_amdgcn_mfma_f32_16x16x32_bf16(a[1][kt], b, acc1, 0, 0, 0);
        }
        const float bb = bo[col];
#pragma unroll
        for (int j = 0; j < 4; ++j) {
            const int r0 = m0 + lg * 4 + j;
            if (r0 < N)
                out[(size_t)r0 * 128 + col] =
                    acc0[j] + bb + nodes[(size_t)r0 * 128 + col];
            const int r1 = m0 + 16 + lg * 4 + j;
            if (r1 < N)
                out[(size_t)r1 * 128 + col] =
                    acc1[j] + bb + nodes[(size_t)r1 * 128 + col];
        }
    }
}

// ---------------------------------------------------------------------------
// Fallback kernels (measured-correct mid path, used only if ws too small)
// ---------------------------------------------------------------------------
__global__ __launch_bounds__(256) void edge_kernel(
    const int* __restrict__ senders, const int* __restrict__ receivers,
    const bf16_t* __restrict__ qb, const bf16_t* __restrict__ kb,
    const bf16_t* __restrict__ vb,
    float* __restrict__ agg, int E)
{
    const int wid = threadIdx.x >> 6;
    const int lane = threadIdx.x & 63;
    const int e = blockIdx.x * 4 + wid;
    if (e >= E) return;

    const int s = senders[e];
    const int r = receivers[e];

    const int c = lane * 2;
    const unsigned int qu = *(const unsigned int*)(qb + (size_t)s * N_DIM + c);
    const unsigned int ku = *(const unsigned int*)(kb + (size_t)r * N_DIM + c);
    const unsigned int vu = *(const unsigned int*)(vb + (size_t)s * N_DIM + c);

    const float qx = lof(qu), qy = hif(qu);
    const float kx = lof(ku), ky = hif(ku);

    float p = qx * kx + qy * ky;
    p += __shfl_xor(p, 1);
    p += __shfl_xor(p, 2);
    p += __shfl_xor(p, 4);
    p += __shfl_xor(p, 8);

    const float scale = 0.17677669529663687f;
    const float s0 = __shfl(p, 0)  * scale;
    const float s1 = __shfl(p, 16) * scale;
    const float s2 = __shfl(p, 32) * scale;
    const float s3 = __shfl(p, 48) * scale;

    const float m = fmaxf(fmaxf(s0, s1), fmaxf(s2, s3));
    const float e0 = __expf(s0 - m);
    const float e1 = __expf(s1 - m);
    const float e2 = __expf(s2 - m);
    const float e3 = __expf(s3 - m);
    const float inv = 1.0f / (e0 + e1 + e2 + e3);

    const int h = lane >> 4;
    const float aw = (h == 0 ? e0 : h == 1 ? e1 : h == 2 ? e2 : e3) * inv;

    const float wx = lof(vu) * aw;
    const float wy = hif(vu) * aw;

    float* dst = agg + (size_t)r * N_DIM + c;
    atomicAdd(dst, wx);
    atomicAdd(dst + 1, wy);
}

__global__ __launch_bounds__(256) void out_mfma_kernel(
    const float* __restrict__ nodes,
    const bf16_t* __restrict__ Wot,
    const float* __restrict__ bo,
    float* __restrict__ out, int N)
{
    __shared__ bf16_t lds_a[32 * LDA_STRIDE];
    const int tid = threadIdx.x;
    const int m0 = blockIdx.x * 32;

#pragma unroll
    for (int i = 0; i < 4; ++i) {
        const int f = tid + 256 * i;
        const int row = f >> 5, c4 = f & 31;
        const int g = m0 + row;
        float4 v = make_float4(0.f, 0.f, 0.f, 0.f);
        if (g < N) v = ((const float4*)out)[(size_t)g * 32 + c4];
        ushort4 u;
        u.x = f32_to_bf16(v.x); u.y = f32_to_bf16(v.y);
        u.z = f32_to_bf16(v.z); u.w = f32_to_bf16(v.w);
        *(ushort4*)(lds_a + row * LDA_STRIDE + c4 * 4) = u;
    }
    __syncthreads();

    const int w  = tid >> 6;
    const int l  = tid & 63;
    const int lr = l & 15;
    const int lg = l >> 4;

    bf16x8 a[2][4];
#pragma unroll
    for (int mt = 0; mt < 2; ++mt)
#pragma unroll
        for (int kt = 0; kt < 4; ++kt)
            a[mt][kt] = *(const bf16x8*)(lds_a + (mt * 16 + lr) * LDA_STRIDE
                                         + kt * 32 + lg * 8);

#pragma unroll
    for (int ni = 0; ni < 2; ++ni) {
        const int nt = w * 2 + ni;
        const int col = nt * 16 + lr;
        f32x4 acc0 = {0.f, 0.f, 0.f, 0.f};
        f32x4 acc1 = {0.f, 0.f, 0.f, 0.f};
#pragma unroll
        for (int kt = 0; kt < 4; ++kt) {
            const bf16x8 b = *(const bf16x8*)(Wot + (size_t)col * 128
                                              + kt * 32 + lg * 8);
            acc0 = __builtin_amdgcn_mfma_f32_16x16x32_bf16(a[0][kt], b, acc0, 0, 0, 0);
            acc1 = __builtin_amdgcn_mfma_f32_16x16x32_bf16(a[1][kt], b, acc1, 0, 0, 0);
        }
        const float bb = bo[col];
#pragma unroll
        for (int j = 0; j < 4; ++j) {
            const int r0 = m0 + lg * 4 + j;
            if (r0 < N)
                out[(size_t)r0 * 128 + col] =
                    acc0[j] + bb + nodes[(size_t)r0 * 128 + col];
            const int r1 = m0 + 16 + lg * 4 + j;
            if (r1 < N)
                out[(size_t)r1 * 128 + col] =
                    acc1[j] + bb + nodes[(size_t)r1 * 128 + col];
        }
    }
}

// ---------------------------------------------------------------------------
extern "C" void kernel_launch(void* const* d_in, const int* in_sizes, int n_in,
                              void* d_out, int out_size, void* d_ws, size_t ws_size,
                              hipStream_t stream)
{
    const float* nodes   = (const float*)d_in[0];
    const int* senders   = (const int*)d_in[1];
    const int* receivers = (const int*)d_in[2];
    const float* Wq = (const float*)d_in[3];
    const float* bq = (const float*)d_in[4];
    const float* Wk = (const float*)d_in[5];
    const float* bk = (const float*)d_in[6];
    const float* Wv = (const float*)d_in[7];
    const float* bv = (const float*)d_in[8];
    const float* Wo = (const float*)d_in[9];
    const float* bo = (const float*)d_in[10];

    const int N = in_sizes[0] / N_DIM;   // 100000
    const int E = in_sizes[1];           // 600000

    float* out = (float*)d_out;
    char* ws = (char*)d_ws;

    const size_t row_bytes = (size_t)N * N_DIM * sizeof(bf16_t);
    size_t off = 0;
    bf16_t* qb    = (bf16_t*)(ws + off); off += row_bytes;
    bf16_t* kb    = (bf16_t*)(ws + off); off += row_bytes;
    bf16_t* vb    = (bf16_t*)(ws + off); off += row_bytes;
    bf16_t* Wt    = (bf16_t*)(ws + off); off += 384 * 128 * sizeof(bf16_t);
    bf16_t* Wot   = (bf16_t*)(ws + off); off += 128 * 128 * sizeof(bf16_t);
    bf16_t* agg_b = (bf16_t*)(ws + off); off += row_bytes;
    int* cnt      = (int*)(ws + off);    off += (size_t)N * 4;
    int* starts   = (int*)(ws + off);    off += (size_t)(N + 1) * 4;
    int* cursor   = (int*)(ws + off);    off += (size_t)N * 4;
    int* elist    = (int*)(ws + off);    off += (size_t)E * 4;
    unsigned int* wlist2 = (unsigned int*)(ws + off); off += (size_t)E * 8;
    int* bsum     = (int*)(ws + off);    off += 256 * 4;
    int* boff     = (int*)(ws + off);    off += 256 * 4;
    const size_t need_csr = off;
    const size_t need_mid = 3 * row_bytes + (384 + 128) * 128 * sizeof(bf16_t);

    // attn2 (E*8 bytes = 4.8MB) lives in the dead prefix of agg_b (25.6MB):
    // written by edge_attn, read by scatter, then agg_b is overwritten later.
    unsigned int* attn2 = (unsigned int*)agg_b;

    const int nb = (N + 1023) / 1024;    // scan blocks (98 for N=100000)

    if (ws_size >= need_csr && nb <= 256) {
        transpose_w_kernel<<<512, 128, 0, stream>>>(Wq, Wk, Wv, Wo, Wt, Wot);
        qkv_mfma_kernel<<<(N + 31) / 32, 256, 0, stream>>>(
            nodes, Wt, bq, bk, bv, qb, kb, vb, N);

        edge_attn_kernel<<<(E + 255) / 256, 256, 0, stream>>>(
            senders, receivers, qb, kb, attn2, E);

        hipMemsetAsync(cnt, 0, (size_t)N * 4, stream);
        hist_kernel<<<(E + 255) / 256, 256, 0, stream>>>(receivers, cnt, E);
        scan_block_kernel<<<nb, 256, 0, stream>>>(cnt, starts, bsum, N);
        scan_top_kernel<<<1, 256, 0, stream>>>(bsum, boff, starts, nb, N);
        scan_add_kernel<<<nb, 256, 0, stream>>>(starts, cursor, boff, N);
        scatter_kernel<<<(E + 255) / 256, 256, 0, stream>>>(
            senders, receivers, attn2, cursor, elist, wlist2, E);

        agg2_kernel<<<(N + 3) / 4, 256, 0, stream>>>(
            starts, elist, wlist2, vb, agg_b, N);

        out_mfma_b_kernel<<<(N + 31) / 32, 256, 0, stream>>>(
            nodes, agg_b, Wot, bo, out, N);
    } else if (ws_size >= need_mid) {
        hipMemsetAsync(d_out, 0, (size_t)N * N_DIM * sizeof(float), stream);
        transpose_w_kernel<<<512, 128, 0, stream>>>(Wq, Wk, Wv, Wo, Wt, Wot);
        qkv_mfma_kernel<<<(N + 31) / 32, 256, 0, stream>>>(
            nodes, Wt, bq, bk, bv, qb, kb, vb, N);
        edge_kernel<<<(E + 3) / 4, 256, 0, stream>>>(
            senders, receivers, qb, kb, vb, out, E);
        out_mfma_kernel<<<(N + 31) / 32, 256, 0, stream>>>(
            nodes, Wot, bo, out, N);
    }
}

// Round 11
// 346.988 us; speedup vs baseline: 1.1357x; 1.1357x over previous
//
#include <hip/hip_runtime.h>
#include <hip/hip_bf16.h>

#define N_DIM 128
#define NHEADS 4
#define HEAD_DIM 32

typedef unsigned short bf16_t;
typedef short bf16x8 __attribute__((ext_vector_type(8)));
typedef float f32x4 __attribute__((ext_vector_type(4)));

__device__ __forceinline__ float bf16_to_f32(unsigned int u16) {
    union { unsigned int i; float f; } x;
    x.i = u16 << 16;
    return x.f;
}

// low/high bf16 of a packed uint -> f32
__device__ __forceinline__ float lof(unsigned int u) {
    union { unsigned int i; float f; } x; x.i = u << 16; return x.f;
}
__device__ __forceinline__ float hif(unsigned int u) {
    union { unsigned int i; float f; } x; x.i = u & 0xffff0000u; return x.f;
}

__device__ __forceinline__ bf16_t f32_to_bf16(float f) {
    union { float f; unsigned int i; } x;
    x.f = f;
    unsigned int r = x.i + 0x7FFFu + ((x.i >> 16) & 1u);  // RNE
    return (bf16_t)(r >> 16);
}

// padded LDS stride for the 32x128 bf16 A-tile: 136 elems = 272 B
#define LDA_STRIDE 136

// ---------------------------------------------------------------------------
// K0: transpose W's to bf16.  Wt[384][128] = {Wq^T,Wk^T,Wv^T}, Wot = Wo^T.
// ---------------------------------------------------------------------------
__global__ __launch_bounds__(128) void transpose_w_kernel(
    const float* __restrict__ Wq, const float* __restrict__ Wk,
    const float* __restrict__ Wv, const float* __restrict__ Wo,
    bf16_t* __restrict__ Wt, bf16_t* __restrict__ Wot)
{
    const int n = blockIdx.x;    // 0..511
    const int k = threadIdx.x;   // 0..127
    const float* W; bf16_t* dst; int nl;
    if (n < 128)      { W = Wq; nl = n;       dst = Wt  + n * 128; }
    else if (n < 256) { W = Wk; nl = n - 128; dst = Wt  + n * 128; }
    else if (n < 384) { W = Wv; nl = n - 256; dst = Wt  + n * 128; }
    else              { W = Wo; nl = n - 384; dst = Wot + (n - 384) * 128; }
    dst[k] = f32_to_bf16(W[k * 128 + nl]);
}

// ---------------------------------------------------------------------------
// K1 (MFMA, swapped operands): q/k/v projections, bf16 out.
// mfma(w_frag, x_frag): D col = lane&15 -> NODE ROW, D row = (lane>>4)*4+j
// -> FEATURE.  Each lane packs 4 consecutive features -> one 8B store.
// ---------------------------------------------------------------------------
__global__ __launch_bounds__(256) void qkv_mfma_kernel(
    const float* __restrict__ nodes,
    const bf16_t* __restrict__ Wt,
    const float* __restrict__ bq, const float* __restrict__ bk,
    const float* __restrict__ bv,
    bf16_t* __restrict__ qb, bf16_t* __restrict__ kb, bf16_t* __restrict__ vb,
    int N)
{
    __shared__ bf16_t lds_a[32 * LDA_STRIDE];
    const int tid = threadIdx.x;
    const int m0 = blockIdx.x * 32;

    // stage 32x128 f32 -> bf16 LDS (1024 float4, 4 per thread)
#pragma unroll
    for (int i = 0; i < 4; ++i) {
        const int f = tid + 256 * i;
        const int row = f >> 5, c4 = f & 31;
        const int g = m0 + row;
        float4 v = make_float4(0.f, 0.f, 0.f, 0.f);
        if (g < N) v = ((const float4*)nodes)[(size_t)g * 32 + c4];
        ushort4 u;
        u.x = f32_to_bf16(v.x); u.y = f32_to_bf16(v.y);
        u.z = f32_to_bf16(v.z); u.w = f32_to_bf16(v.w);
        *(ushort4*)(lds_a + row * LDA_STRIDE + c4 * 4) = u;
    }
    __syncthreads();

    const int w  = tid >> 6;
    const int l  = tid & 63;
    const int lr = l & 15;   // node row (x-frag non-k idx) / feature row (w-frag)
    const int lg = l >> 4;   // k-group 0..3

    // x fragments (used as the MFMA *B* operand)
    bf16x8 a[2][4];
#pragma unroll
    for (int mt = 0; mt < 2; ++mt)
#pragma unroll
        for (int kt = 0; kt < 4; ++kt)
            a[mt][kt] = *(const bf16x8*)(lds_a + (mt * 16 + lr) * LDA_STRIDE
                                         + kt * 32 + lg * 8);

#pragma unroll
    for (int ni = 0; ni < 6; ++ni) {
        const int nt = w * 6 + ni;          // 0..23
        f32x4 acc0 = {0.f, 0.f, 0.f, 0.f};
        f32x4 acc1 = {0.f, 0.f, 0.f, 0.f};
#pragma unroll
        for (int kt = 0; kt < 4; ++kt) {
            // w fragment (used as the MFMA *A* operand): feature = nt*16+lr
            const bf16x8 b = *(const bf16x8*)(Wt + (size_t)(nt * 16 + lr) * 128
                                              + kt * 32 + lg * 8);
            acc0 = __builtin_amdgcn_mfma_f32_16x16x32_bf16(b, a[0][kt], acc0, 0, 0, 0);
            acc1 = __builtin_amdgcn_mfma_f32_16x16x32_bf16(b, a[1][kt], acc1, 0, 0, 0);
        }
        const int fb = nt * 16 + lg * 4;    // this lane's 4 consecutive features
        bf16_t* dst; int cl; const float* bias;
        if (nt < 8)       { dst = qb; cl = fb;       bias = bq; }
        else if (nt < 16) { dst = kb; cl = fb - 128; bias = bk; }
        else              { dst = vb; cl = fb - 256; bias = bv; }
        const float4 b4 = *(const float4*)(bias + cl);

        uint2 p0, p1;
        p0.x = (unsigned)f32_to_bf16(acc0[0] + b4.x)
             | ((unsigned)f32_to_bf16(acc0[1] + b4.y) << 16);
        p0.y = (unsigned)f32_to_bf16(acc0[2] + b4.z)
             | ((unsigned)f32_to_bf16(acc0[3] + b4.w) << 16);
        p1.x = (unsigned)f32_to_bf16(acc1[0] + b4.x)
             | ((unsigned)f32_to_bf16(acc1[1] + b4.y) << 16);
        p1.y = (unsigned)f32_to_bf16(acc1[2] + b4.z)
             | ((unsigned)f32_to_bf16(acc1[3] + b4.w) << 16);

        const int r0 = m0 + lr;        // mt=0 node row (D col = lane&15)
        const int r1 = m0 + 16 + lr;   // mt=1
        if (r0 < N) *(uint2*)(dst + (size_t)r0 * 128 + cl) = p0;
        if (r1 < N) *(uint2*)(dst + (size_t)r1 * 128 + cl) = p1;
    }
}

// ---------------------------------------------------------------------------
// CSR build: histogram -> 2-level exclusive scan -> scatter   (measured-good)
// ---------------------------------------------------------------------------
__global__ __launch_bounds__(256) void hist_kernel(
    const int* __restrict__ receivers, int* __restrict__ cnt, int E)
{
    const int i = blockIdx.x * 256 + threadIdx.x;
    if (i < E) atomicAdd(&cnt[receivers[i]], 1);
}

__global__ __launch_bounds__(256) void scan_block_kernel(
    const int* __restrict__ cnt, int* __restrict__ starts,
    int* __restrict__ bsum, int N)
{
    __shared__ int sc[256];
    const int t = threadIdx.x;
    const int base = blockIdx.x * 1024 + t * 4;
    int v0 = (base + 0 < N) ? cnt[base + 0] : 0;
    int v1 = (base + 1 < N) ? cnt[base + 1] : 0;
    int v2 = (base + 2 < N) ? cnt[base + 2] : 0;
    int v3 = (base + 3 < N) ? cnt[base + 3] : 0;
    const int s = v0 + v1 + v2 + v3;
    sc[t] = s;
    __syncthreads();
    for (int off = 1; off < 256; off <<= 1) {
        int x = (t >= off) ? sc[t - off] : 0;
        __syncthreads();
        sc[t] += x;
        __syncthreads();
    }
    int excl = sc[t] - s;
    if (base + 0 < N) starts[base + 0] = excl;
    if (base + 1 < N) starts[base + 1] = excl + v0;
    if (base + 2 < N) starts[base + 2] = excl + v0 + v1;
    if (base + 3 < N) starts[base + 3] = excl + v0 + v1 + v2;
    if (t == 255) bsum[blockIdx.x] = sc[255];
}

__global__ __launch_bounds__(256) void scan_top_kernel(
    const int* __restrict__ bsum, int* __restrict__ boff,
    int* __restrict__ starts, int nb, int N)
{
    __shared__ int sc[256];
    const int t = threadIdx.x;
    const int s = (t < nb) ? bsum[t] : 0;
    sc[t] = s;
    __syncthreads();
    for (int off = 1; off < 256; off <<= 1) {
        int x = (t >= off) ? sc[t - off] : 0;
        __syncthreads();
        sc[t] += x;
        __syncthreads();
    }
    if (t < nb) boff[t] = sc[t] - s;
    if (t == 255) starts[N] = sc[255];
}

__global__ __launch_bounds__(256) void scan_add_kernel(
    int* __restrict__ starts, int* __restrict__ cursor,
    const int* __restrict__ boff, int N)
{
    const int t = threadIdx.x;
    const int base = blockIdx.x * 1024 + t * 4;
    const int o = boff[blockIdx.x];
#pragma unroll
    for (int k = 0; k < 4; ++k) {
        const int i = base + k;
        if (i < N) {
            const int v = starts[i] + o;
            starts[i] = v;
            cursor[i] = v;
        }
    }
}

__global__ __launch_bounds__(256) void scatter_kernel(
    const int* __restrict__ senders, const int* __restrict__ receivers,
    int* __restrict__ cursor, int* __restrict__ elist, int E)
{
    const int i = blockIdx.x * 256 + threadIdx.x;
    if (i < E) {
        const int pos = atomicAdd(&cursor[receivers[i]], 1);
        elist[pos] = senders[i];
    }
}

// ---------------------------------------------------------------------------
// K2 (CSR aggregate): one wave per receiver.  (reverted to measured round-9)
// ---------------------------------------------------------------------------
__global__ __launch_bounds__(256) void agg_kernel(
    const int* __restrict__ starts, const int* __restrict__ elist,
    const bf16_t* __restrict__ qb, const bf16_t* __restrict__ kb,
    const bf16_t* __restrict__ vb,
    bf16_t* __restrict__ agg_b, int N)
{
    const int r = blockIdx.x * 4 + (threadIdx.x >> 6);
    const int lane = threadIdx.x & 63;
    if (r >= N) return;

    const int start = starts[r];
    const int end   = starts[r + 1];
    const int c = lane * 2;

    const unsigned int ku = *(const unsigned int*)(kb + (size_t)r * N_DIM + c);
    const float kx = lof(ku), ky = hif(ku);

    float ax = 0.f, ay = 0.f;
    const float scale = 0.17677669529663687f;  // 1/sqrt(32)
    const int h = lane >> 4;

    for (int j0 = start; j0 < end; j0 += 64) {
        const int ids = (j0 + lane < end) ? elist[j0 + lane] : 0;
        const int jm = min(64, end - j0);
        for (int j = 0; j < jm; ++j) {
            const int s = __shfl(ids, j);
            const unsigned int qu =
                *(const unsigned int*)(qb + (size_t)s * N_DIM + c);
            const unsigned int vu =
                *(const unsigned int*)(vb + (size_t)s * N_DIM + c);
            const float qx = lof(qu), qy = hif(qu);

            float p = qx * kx + qy * ky;
            p += __shfl_xor(p, 1);
            p += __shfl_xor(p, 2);
            p += __shfl_xor(p, 4);
            p += __shfl_xor(p, 8);

            const float s0 = __shfl(p, 0)  * scale;
            const float s1 = __shfl(p, 16) * scale;
            const float s2 = __shfl(p, 32) * scale;
            const float s3 = __shfl(p, 48) * scale;

            const float m = fmaxf(fmaxf(s0, s1), fmaxf(s2, s3));
            const float e0 = __expf(s0 - m);
            const float e1 = __expf(s1 - m);
            const float e2 = __expf(s2 - m);
            const float e3 = __expf(s3 - m);
            const float inv = 1.0f / (e0 + e1 + e2 + e3);
            const float aw = (h == 0 ? e0 : h == 1 ? e1 : h == 2 ? e2 : e3) * inv;

            ax = fmaf(lof(vu), aw, ax);
            ay = fmaf(hif(vu), aw, ay);
        }
    }

    const unsigned int packed =
        (unsigned int)f32_to_bf16(ax) | ((unsigned int)f32_to_bf16(ay) << 16);
    *(unsigned int*)(agg_b + (size_t)r * N_DIM + c) = packed;
}

// ---------------------------------------------------------------------------
// K3 (MFMA, swapped operands): out = agg_b @ Wo + bo + nodes.
// Each lane: 4 consecutive f32 outputs -> float4 store; float4 residual load.
// ---------------------------------------------------------------------------
__global__ __launch_bounds__(256) void out_mfma_b_kernel(
    const float* __restrict__ nodes,
    const bf16_t* __restrict__ agg_b,
    const bf16_t* __restrict__ Wot,
    const float* __restrict__ bo,
    float* __restrict__ out, int N)
{
    __shared__ bf16_t lds_a[32 * LDA_STRIDE];
    const int tid = threadIdx.x;
    const int m0 = blockIdx.x * 32;

#pragma unroll
    for (int i = 0; i < 4; ++i) {
        const int f = tid + 256 * i;
        const int row = f >> 5, c4 = f & 31;
        const int g = m0 + row;
        ushort4 u = make_ushort4(0, 0, 0, 0);
        if (g < N) u = ((const ushort4*)(agg_b + (size_t)g * N_DIM))[c4];
        *(ushort4*)(lds_a + row * LDA_STRIDE + c4 * 4) = u;
    }
    __syncthreads();

    const int w  = tid >> 6;
    const int l  = tid & 63;
    const int lr = l & 15;
    const int lg = l >> 4;

    bf16x8 a[2][4];
#pragma unroll
    for (int mt = 0; mt < 2; ++mt)
#pragma unroll
        for (int kt = 0; kt < 4; ++kt)
            a[mt][kt] = *(const bf16x8*)(lds_a + (mt * 16 + lr) * LDA_STRIDE
                                         + kt * 32 + lg * 8);

#pragma unroll
    for (int ni = 0; ni < 2; ++ni) {
        const int nt = w * 2 + ni;          // 0..7
        f32x4 acc0 = {0.f, 0.f, 0.f, 0.f};
        f32x4 acc1 = {0.f, 0.f, 0.f, 0.f};
#pragma unroll
        for (int kt = 0; kt < 4; ++kt) {
            const bf16x8 b = *(const bf16x8*)(Wot + (size_t)(nt * 16 + lr) * 128
                                              + kt * 32 + lg * 8);
            acc0 = __builtin_amdgcn_mfma_f32_16x16x32_bf16(b, a[0][kt], acc0, 0, 0, 0);
            acc1 = __builtin_amdgcn_mfma_f32_16x16x32_bf16(b, a[1][kt], acc1, 0, 0, 0);
        }
        const int fb = nt * 16 + lg * 4;    // 4 consecutive output features
        const float4 b4 = *(const float4*)(bo + fb);

        const int r0 = m0 + lr;
        const int r1 = m0 + 16 + lr;
        if (r0 < N) {
            const float4 nd = *(const float4*)(nodes + (size_t)r0 * 128 + fb);
            float4 res;
            res.x = acc0[0] + b4.x + nd.x;
            res.y = acc0[1] + b4.y + nd.y;
            res.z = acc0[2] + b4.z + nd.z;
            res.w = acc0[3] + b4.w + nd.w;
            *(float4*)(out + (size_t)r0 * 128 + fb) = res;
        }
        if (r1 < N) {
            const float4 nd = *(const float4*)(nodes + (size_t)r1 * 128 + fb);
            float4 res;
            res.x = acc1[0] + b4.x + nd.x;
            res.y = acc1[1] + b4.y + nd.y;
            res.z = acc1[2] + b4.z + nd.z;
            res.w = acc1[3] + b4.w + nd.w;
            *(float4*)(out + (size_t)r1 * 128 + fb) = res;
        }
    }
}

// ---------------------------------------------------------------------------
// Fallback kernels (measured-correct mid path, used only if ws too small)
// ---------------------------------------------------------------------------
__global__ __launch_bounds__(256) void edge_kernel(
    const int* __restrict__ senders, const int* __restrict__ receivers,
    const bf16_t* __restrict__ qb, const bf16_t* __restrict__ kb,
    const bf16_t* __restrict__ vb,
    float* __restrict__ agg, int E)
{
    const int wid = threadIdx.x >> 6;
    const int lane = threadIdx.x & 63;
    const int e = blockIdx.x * 4 + wid;
    if (e >= E) return;

    const int s = senders[e];
    const int r = receivers[e];

    const int c = lane * 2;
    const unsigned int qu = *(const unsigned int*)(qb + (size_t)s * N_DIM + c);
    const unsigned int ku = *(const unsigned int*)(kb + (size_t)r * N_DIM + c);
    const unsigned int vu = *(const unsigned int*)(vb + (size_t)s * N_DIM + c);

    const float qx = lof(qu), qy = hif(qu);
    const float kx = lof(ku), ky = hif(ku);

    float p = qx * kx + qy * ky;
    p += __shfl_xor(p, 1);
    p += __shfl_xor(p, 2);
    p += __shfl_xor(p, 4);
    p += __shfl_xor(p, 8);

    const float scale = 0.17677669529663687f;
    const float s0 = __shfl(p, 0)  * scale;
    const float s1 = __shfl(p, 16) * scale;
    const float s2 = __shfl(p, 32) * scale;
    const float s3 = __shfl(p, 48) * scale;

    const float m = fmaxf(fmaxf(s0, s1), fmaxf(s2, s3));
    const float e0 = __expf(s0 - m);
    const float e1 = __expf(s1 - m);
    const float e2 = __expf(s2 - m);
    const float e3 = __expf(s3 - m);
    const float inv = 1.0f / (e0 + e1 + e2 + e3);

    const int h = lane >> 4;
    const float aw = (h == 0 ? e0 : h == 1 ? e1 : h == 2 ? e2 : e3) * inv;

    const float wx = lof(vu) * aw;
    const float wy = hif(vu) * aw;

    float* dst = agg + (size_t)r * N_DIM + c;
    atomicAdd(dst, wx);
    atomicAdd(dst + 1, wy);
}

__global__ __launch_bounds__(256) void out_mfma_kernel(
    const float* __restrict__ nodes,
    const bf16_t* __restrict__ Wot,
    const float* __restrict__ bo,
    float* __restrict__ out, int N)
{
    __shared__ bf16_t lds_a[32 * LDA_STRIDE];
    const int tid = threadIdx.x;
    const int m0 = blockIdx.x * 32;

#pragma unroll
    for (int i = 0; i < 4; ++i) {
        const int f = tid + 256 * i;
        const int row = f >> 5, c4 = f & 31;
        const int g = m0 + row;
        float4 v = make_float4(0.f, 0.f, 0.f, 0.f);
        if (g < N) v = ((const float4*)out)[(size_t)g * 32 + c4];
        ushort4 u;
        u.x = f32_to_bf16(v.x); u.y = f32_to_bf16(v.y);
        u.z = f32_to_bf16(v.z); u.w = f32_to_bf16(v.w);
        *(ushort4*)(lds_a + row * LDA_STRIDE + c4 * 4) = u;
    }
    __syncthreads();

    const int w  = tid >> 6;
    const int l  = tid & 63;
    const int lr = l & 15;
    const int lg = l >> 4;

    bf16x8 a[2][4];
#pragma unroll
    for (int mt = 0; mt < 2; ++mt)
#pragma unroll
        for (int kt = 0; kt < 4; ++kt)
            a[mt][kt] = *(const bf16x8*)(lds_a + (mt * 16 + lr) * LDA_STRIDE
                                         + kt * 32 + lg * 8);

#pragma unroll
    for (int ni = 0; ni < 2; ++ni) {
        const int nt = w * 2 + ni;
        const int col = nt * 16 + lr;
        f32x4 acc0 = {0.f, 0.f, 0.f, 0.f};
        f32x4 acc1 = {0.f, 0.f, 0.f, 0.f};
#pragma unroll
        for (int kt = 0; kt < 4; ++kt) {
            const bf16x8 b = *(const bf16x8*)(Wot + (size_t)col * 128
                                              + kt * 32 + lg * 8);
            acc0 = __builtin_amdgcn_mfma_f32_16x16x32_bf16(a[0][kt], b, acc0, 0, 0, 0);
            acc1 = __builtin_amdgcn_mfma_f32_16x16x32_bf16(a[1][kt], b, acc1, 0, 0, 0);
        }
        const float bb = bo[col];
#pragma unroll
        for (int j = 0; j < 4; ++j) {
            const int r0 = m0 + lg * 4 + j;
            if (r0 < N)
                out[(size_t)r0 * 128 + col] =
                    acc0[j] + bb + nodes[(size_t)r0 * 128 + col];
            const int r1 = m0 + 16 + lg * 4 + j;
            if (r1 < N)
                out[(size_t)r1 * 128 + col] =
                    acc1[j] + bb + nodes[(size_t)r1 * 128 + col];
        }
    }
}

// ---------------------------------------------------------------------------
extern "C" void kernel_launch(void* const* d_in, const int* in_sizes, int n_in,
                              void* d_out, int out_size, void* d_ws, size_t ws_size,
                              hipStream_t stream)
{
    const float* nodes   = (const float*)d_in[0];
    const int* senders   = (const int*)d_in[1];
    const int* receivers = (const int*)d_in[2];
    const float* Wq = (const float*)d_in[3];
    const float* bq = (const float*)d_in[4];
    const float* Wk = (const float*)d_in[5];
    const float* bk = (const float*)d_in[6];
    const float* Wv = (const float*)d_in[7];
    const float* bv = (const float*)d_in[8];
    const float* Wo = (const float*)d_in[9];
    const float* bo = (const float*)d_in[10];

    const int N = in_sizes[0] / N_DIM;   // 100000
    const int E = in_sizes[1];           // 600000

    float* out = (float*)d_out;
    char* ws = (char*)d_ws;

    const size_t row_bytes = (size_t)N * N_DIM * sizeof(bf16_t);
    size_t off = 0;
    bf16_t* qb    = (bf16_t*)(ws + off); off += row_bytes;
    bf16_t* kb    = (bf16_t*)(ws + off); off += row_bytes;
    bf16_t* vb    = (bf16_t*)(ws + off); off += row_bytes;
    bf16_t* Wt    = (bf16_t*)(ws + off); off += 384 * 128 * sizeof(bf16_t);
    bf16_t* Wot   = (bf16_t*)(ws + off); off += 128 * 128 * sizeof(bf16_t);
    bf16_t* agg_b = (bf16_t*)(ws + off); off += row_bytes;
    int* cnt      = (int*)(ws + off);    off += (size_t)N * 4;
    int* starts   = (int*)(ws + off);    off += (size_t)(N + 1) * 4;
    int* cursor   = (int*)(ws + off);    off += (size_t)N * 4;
    int* elist    = (int*)(ws + off);    off += (size_t)E * 4;
    int* bsum     = (int*)(ws + off);    off += 256 * 4;
    int* boff     = (int*)(ws + off);    off += 256 * 4;
    const size_t need_csr = off;
    const size_t need_mid = 3 * row_bytes + (384 + 128) * 128 * sizeof(bf16_t);

    const int nb = (N + 1023) / 1024;    // scan blocks (98 for N=100000)

    if (ws_size >= need_csr && nb <= 256) {
        transpose_w_kernel<<<512, 128, 0, stream>>>(Wq, Wk, Wv, Wo, Wt, Wot);
        qkv_mfma_kernel<<<(N + 31) / 32, 256, 0, stream>>>(
            nodes, Wt, bq, bk, bv, qb, kb, vb, N);

        hipMemsetAsync(cnt, 0, (size_t)N * 4, stream);
        hist_kernel<<<(E + 255) / 256, 256, 0, stream>>>(receivers, cnt, E);
        scan_block_kernel<<<nb, 256, 0, stream>>>(cnt, starts, bsum, N);
        scan_top_kernel<<<1, 256, 0, stream>>>(bsum, boff, starts, nb, N);
        scan_add_kernel<<<nb, 256, 0, stream>>>(starts, cursor, boff, N);
        scatter_kernel<<<(E + 255) / 256, 256, 0, stream>>>(
            senders, receivers, cursor, elist, E);

        agg_kernel<<<(N + 3) / 4, 256, 0, stream>>>(
            starts, elist, qb, kb, vb, agg_b, N);

        out_mfma_b_kernel<<<(N + 31) / 32, 256, 0, stream>>>(
            nodes, agg_b, Wot, bo, out, N);
    } else if (ws_size >= need_mid) {
        hipMemsetAsync(d_out, 0, (size_t)N * N_DIM * sizeof(float), stream);
        transpose_w_kernel<<<512, 128, 0, stream>>>(Wq, Wk, Wv, Wo, Wt, Wot);
        qkv_mfma_kernel<<<(N + 31) / 32, 256, 0, stream>>>(
            nodes, Wt, bq, bk, bv, qb, kb, vb, N);
        edge_kernel<<<(E + 3) / 4, 256, 0, stream>>>(
            senders, receivers, qb, kb, vb, out, E);
        out_mfma_kernel<<<(N + 31) / 32, 256, 0, stream>>>(
            nodes, Wot, bo, out, N);
    }
}